// Round 1
// baseline (868.577 us; speedup 1.0000x reference)
//
#include <hip/hip_runtime.h>
#include <math.h>

#define T_LEN 2048
#define NF    16
#define NTH   256
#define NOUT  3146

// ---------------- block reductions (256 threads = 4 waves of 64) ----------------
__device__ __forceinline__ float wred_sum(float v) {
  v += __shfl_down(v, 32);
  v += __shfl_down(v, 16);
  v += __shfl_down(v, 8);
  v += __shfl_down(v, 4);
  v += __shfl_down(v, 2);
  v += __shfl_down(v, 1);
  return v;
}
__device__ __forceinline__ float wred_min(float v) {
  v = fminf(v, __shfl_down(v, 32));
  v = fminf(v, __shfl_down(v, 16));
  v = fminf(v, __shfl_down(v, 8));
  v = fminf(v, __shfl_down(v, 4));
  v = fminf(v, __shfl_down(v, 2));
  v = fminf(v, __shfl_down(v, 1));
  return v;
}
__device__ __forceinline__ float wred_max(float v) {
  v = fmaxf(v, __shfl_down(v, 32));
  v = fmaxf(v, __shfl_down(v, 16));
  v = fmaxf(v, __shfl_down(v, 8));
  v = fmaxf(v, __shfl_down(v, 4));
  v = fmaxf(v, __shfl_down(v, 2));
  v = fmaxf(v, __shfl_down(v, 1));
  return v;
}

__device__ __forceinline__ float block_sum(float v, float* red, int tid) {
  v = wred_sum(v);
  if ((tid & 63) == 0) red[tid >> 6] = v;
  __syncthreads();
  if (tid == 0) red[4] = red[0] + red[1] + red[2] + red[3];
  __syncthreads();
  float r = red[4];
  __syncthreads();
  return r;
}
__device__ __forceinline__ float block_min(float v, float* red, int tid) {
  v = wred_min(v);
  if ((tid & 63) == 0) red[tid >> 6] = v;
  __syncthreads();
  if (tid == 0) red[4] = fminf(fminf(red[0], red[1]), fminf(red[2], red[3]));
  __syncthreads();
  float r = red[4];
  __syncthreads();
  return r;
}
__device__ __forceinline__ float block_max(float v, float* red, int tid) {
  v = wred_max(v);
  if ((tid & 63) == 0) red[tid >> 6] = v;
  __syncthreads();
  if (tid == 0) red[4] = fmaxf(fmaxf(red[0], red[1]), fmaxf(red[2], red[3]));
  __syncthreads();
  float r = red[4];
  __syncthreads();
  return r;
}

// agg4 over a tiny register array (n=9), fully unrolled (rule: no runtime-indexed reg arrays)
__device__ __forceinline__ void agg4_9(const float* v, float* om, float* ov, float* os, float* ok) {
  const float fn = 9.0f;
  float s = 0.f;
#pragma unroll
  for (int i = 0; i < 9; i++) s += v[i];
  float m = s / fn;
  float c2 = 0.f, c3 = 0.f, c4 = 0.f;
#pragma unroll
  for (int i = 0; i < 9; i++) {
    float c = v[i] - m;
    float cc = c * c;
    c2 += cc; c3 += cc * c; c4 += cc * cc;
  }
  float var = c2 / fn;
  float sd = (var > 0.f) ? sqrtf(var) : 0.f;
  float sk = (sd > 0.f) ? fn / ((fn - 1.f) * (fn - 2.f)) * (c3 / (sd * sd * sd)) : 0.f;
  float k22 = c2 * c2;
  float al = fn * (fn + 1.f) * (fn - 1.f) / ((fn - 2.f) * (fn - 3.f));
  float ku = ((k22 > 0.f) ? al * c4 / k22 : 0.f)
             - 3.f * (fn - 1.f) * (fn - 1.f) / ((fn - 2.f) * (fn - 3.f));
  *om = m; *ov = var; *os = sk; *ok = ku;
}

__global__ __launch_bounds__(NTH)
void ts_feat_kernel(const float* __restrict__ x, float* __restrict__ out) {
  __shared__ float a[T_LEN];   // original series
  __shared__ float sb[T_LEN];  // sort buffer, then FFT real
  __shared__ float sc[T_LEN];  // FFT imag
  __shared__ float red[8];
  __shared__ float scal[48];

  const int tid = threadIdx.x;
  const int bf = blockIdx.x;
  const int b = bf >> 4;
  const int f = bf & 15;
  const float* xp = x + ((size_t)b * T_LEN) * NF + f;
  float* op = out + (size_t)bf * NOUT;

  for (int t = tid; t < T_LEN; t += NTH) {
    float v = xp[(size_t)t * NF];
    a[t] = v;
    sb[t] = v;
  }
  __syncthreads();

  const float fT = (float)T_LEN;

  // ---- pass 1: raw sums, min/max ----
  float s1 = 0.f, s2 = 0.f, mn = 3.4e38f, mx = -3.4e38f;
  for (int t = tid; t < T_LEN; t += NTH) {
    float v = a[t];
    s1 += v; s2 += v * v;
    mn = fminf(mn, v); mx = fmaxf(mx, v);
  }
  float S1 = block_sum(s1, red, tid);
  float S2 = block_sum(s2, red, tid);
  float MN = block_min(mn, red, tid);
  float MX = block_max(mx, red, tid);
  float mean = S1 / fT;
  float maxabs = fmaxf(-MN, MX);
  float rms = (S2 / fT > 0.f) ? sqrtf(S2 / fT) : 0.f;

  // ---- pass 2: central moments ----
  float c2 = 0.f, c3 = 0.f, c4 = 0.f;
  for (int t = tid; t < T_LEN; t += NTH) {
    float c = a[t] - mean;
    float cc = c * c;
    c2 += cc; c3 += cc * c; c4 += cc * cc;
  }
  float C2 = block_sum(c2, red, tid);
  float C3 = block_sum(c3, red, tid);
  float C4 = block_sum(c4, red, tid);
  float var = C2 / fT;
  float sd = (var > 0.f) ? sqrtf(var) : 0.f;
  float skw = (sd > 0.f) ? (fT / ((fT - 1.f) * (fT - 2.f))) * (C3 / (sd * sd * sd)) : 0.f;
  float k22 = C2 * C2;
  float alphaT = fT * (fT + 1.f) * (fT - 1.f) / ((fT - 2.f) * (fT - 3.f));
  float kurt = ((k22 > 0.f) ? alphaT * C4 / k22 : 0.f)
               - 3.f * (fT - 1.f) * (fT - 1.f) / ((fT - 2.f) * (fT - 3.f));

  // ---- pass 3: xd = x[t+1] - x[t+2], t = 0..T-3 ----
  float sdl = 0.f, sadl = 0.f, sddl = 0.f;
  for (int t = tid; t < T_LEN - 2; t += NTH) {
    float d = a[t + 1] - a[t + 2];
    sdl += d; sadl += fabsf(d); sddl += d * d;
  }
  float SD  = block_sum(sdl, red, tid);
  float SAD = block_sum(sadl, red, tid);
  float SDD = block_sum(sddl, red, tid);

  // ---- bitonic sort of sb ----
  for (int k = 2; k <= T_LEN; k <<= 1) {
    for (int j = k >> 1; j > 0; j >>= 1) {
      __syncthreads();
      for (int i = tid; i < T_LEN; i += NTH) {
        int ixj = i ^ j;
        if (ixj > i) {
          float vi = sb[i], vj = sb[ixj];
          bool up = ((i & k) == 0);
          bool sw = up ? (vi > vj) : (vi < vj);
          if (sw) { sb[i] = vj; sb[ixj] = vi; }
        }
      }
    }
  }
  __syncthreads();

  float q0 = sb[512], q1 = sb[1024], q2 = sb[1536];
  float tb0 = a[0], tb1 = a[512], tb2 = a[1024], tb3 = a[1536], tb4 = a[2047];

  // ---- pass 4: count_above + crossings for 10 thresholds ----
  // idx: 0 -> 0.0 (s_x), 1 -> mean (s_c), 2..4 -> q0..q2, 5..9 -> tb0..tb4
  float thr0 = 0.f, thr1 = mean, thr2 = q0, thr3 = q1, thr4 = q2;
  float thr5 = tb0, thr6 = tb1, thr7 = tb2, thr8 = tb3, thr9 = tb4;
  int cnt[10]; int crs[10];
#pragma unroll
  for (int j = 0; j < 10; j++) { cnt[j] = 0; crs[j] = 0; }
  for (int t = tid; t < T_LEN; t += NTH) {
    float v = a[t];
    bool has_next = (t < T_LEN - 1);
    float vn = has_next ? a[t + 1] : 0.f;
    float thr_arr0 = thr0, thr_arr1 = thr1, thr_arr2 = thr2, thr_arr3 = thr3, thr_arr4 = thr4;
    float thr_arr5 = thr5, thr_arr6 = thr6, thr_arr7 = thr7, thr_arr8 = thr8, thr_arr9 = thr9;
#define DO_THR(J, THR)                                              \
    {                                                               \
      float d = v - (THR);                                          \
      int s = (d > 0.f) - (d < 0.f);                                \
      cnt[J] += (s == 1);                                           \
      if (has_next) {                                               \
        float dn = vn - (THR);                                      \
        int sn = (dn > 0.f) - (dn < 0.f);                           \
        crs[J] += (s != sn);                                        \
      }                                                             \
    }
    DO_THR(0, thr_arr0) DO_THR(1, thr_arr1) DO_THR(2, thr_arr2) DO_THR(3, thr_arr3) DO_THR(4, thr_arr4)
    DO_THR(5, thr_arr5) DO_THR(6, thr_arr6) DO_THR(7, thr_arr7) DO_THR(8, thr_arr8) DO_THR(9, thr_arr9)
#undef DO_THR
  }
  float CNT[10], CRS[10];
#pragma unroll
  for (int j = 0; j < 10; j++) {
    CNT[j] = block_sum((float)cnt[j], red, tid);
    CRS[j] = block_sum((float)crs[j], red, tid);
  }

  // ---- pass 5: autocorrelation lags 1..9 ----
  float acl[9];
#pragma unroll
  for (int l = 0; l < 9; l++) acl[l] = 0.f;
  for (int t = tid; t < T_LEN; t += NTH) {
    float c0 = a[t] - mean;
#pragma unroll
    for (int l = 1; l <= 9; l++) {
      int t2 = t + l;
      float cl = (t2 < T_LEN) ? (a[t2] - mean) : 0.f;
      acl[l - 1] += c0 * cl;
    }
  }
  float ac[9];
#pragma unroll
  for (int l = 0; l < 9; l++) {
    float s = block_sum(acl[l], red, tid);
    float num = s / (fT - (float)(l + 1));
    ac[l] = (var != 0.f) ? num / var : 0.f;
  }
  float acm, acv, acs, ack;
  agg4_9(ac, &acm, &acv, &acs, &ack);
  float acmax = ac[0];
#pragma unroll
  for (int l = 1; l < 9; l++) acmax = fmaxf(acmax, ac[l]);

  // ---- FFT: 2048-pt radix-2 DIT, bit-reversed input ----
  __syncthreads();
  for (int t = tid; t < T_LEN; t += NTH) {
    int r = (int)(__brev((unsigned)t) >> 21);
    sb[t] = a[r];
    sc[t] = 0.f;
  }
  for (int s = 1; s <= 11; s++) {
    const int half = 1 << (s - 1);
    const float base = -3.14159265358979323846f / (float)half;
    __syncthreads();
    for (int m = tid; m < T_LEN / 2; m += NTH) {
      int pos = m & (half - 1);
      int i0 = ((m >> (s - 1)) << s) | pos;
      int i1 = i0 + half;
      float sn, cs;
      sincosf(base * (float)pos, &sn, &cs);
      float xr = sb[i1], xi = sc[i1];
      float tr = cs * xr - sn * xi;
      float ti = cs * xi + sn * xr;
      float ur = sb[i0], ui = sc[i0];
      sb[i0] = ur + tr; sc[i0] = ui + ti;
      sb[i1] = ur - tr; sc[i1] = ui - ti;
    }
  }
  __syncthreads();

  // ---- amp / ang; amp kept in a[0..1024] (a no longer needed) ----
  float samp = 0.f;
  for (int k = tid; k <= T_LEN / 2; k += NTH) {
    float re = sb[k], im = sc[k];
    float amp = sqrtf(re * re + im * im);
    float ang = atan2f(im, re);
    op[53 + k] = amp;
    op[1078 + k] = ang;
    a[k] = amp;
    samp += amp;
  }
  __syncthreads();
  float S = block_sum(samp, red, tid);
  float invS = (S != 0.f) ? 1.f / S : 0.f;

  for (int k = tid; k <= T_LEN / 2; k += NTH) {
    op[2103 + k] = a[k] * invS;
  }

  // ---- agg4 over amp (n = 1025) ----
  const float fn = 1025.f;
  float am = S / fn;
  float a2 = 0.f, a3 = 0.f, a4 = 0.f;
  for (int k = tid; k <= T_LEN / 2; k += NTH) {
    float c = a[k] - am;
    float cc = c * c;
    a2 += cc; a3 += cc * c; a4 += cc * cc;
  }
  float A2 = block_sum(a2, red, tid);
  float A3 = block_sum(a3, red, tid);
  float A4 = block_sum(a4, red, tid);
  float av = A2 / fn;
  float asd = (av > 0.f) ? sqrtf(av) : 0.f;
  float ask = (asd > 0.f) ? fn / ((fn - 1.f) * (fn - 2.f)) * (A3 / (asd * asd * asd)) : 0.f;
  float ak22 = A2 * A2;
  float aal = fn * (fn + 1.f) * (fn - 1.f) / ((fn - 2.f) * (fn - 3.f));
  float aku = ((ak22 > 0.f) ? aal * A4 / ak22 : 0.f)
              - 3.f * (fn - 1.f) * (fn - 1.f) / ((fn - 2.f) * (fn - 3.f));
  float rm = am * invS;
  float rv = av * invS * invS;
  float rsk = ask, rku = aku;

  // ---- write scalars ----
  if (tid == 0) {
    scal[0] = mean; scal[1] = MN; scal[2] = MX; scal[3] = rms; scal[4] = var; scal[5] = sd;
    scal[6] = skw; scal[7] = kurt;
    scal[8] = SD / (fT - 2.f); scal[9] = SD; scal[10] = SAD / (fT - 2.f);
    scal[11] = S2; scal[12] = maxabs; scal[13] = SAD;
    scal[14] = (SDD > 0.f) ? sqrtf(SDD) : 0.f;
    scal[15] = CNT[0]; scal[16] = CNT[1];
    scal[17] = CNT[5]; scal[18] = CNT[6]; scal[19] = CNT[7]; scal[20] = CNT[8]; scal[21] = CNT[9];
    scal[22] = CRS[0]; scal[23] = CRS[1];
    scal[24] = CRS[2]; scal[25] = CRS[3]; scal[26] = CRS[4];
    scal[27] = CRS[5]; scal[28] = CRS[6]; scal[29] = CRS[7]; scal[30] = CRS[8]; scal[31] = CRS[9];
    scal[32] = a[0];  // amp[0]
    scal[33] = am; scal[34] = av; scal[35] = ask; scal[36] = aku;
    scal[37] = rm; scal[38] = rv; scal[39] = rsk; scal[40] = rku;
    scal[41] = acm; scal[42] = acv; scal[43] = acs; scal[44] = ack;
    scal[45] = q0; scal[46] = q1; scal[47] = q2;
  }
  __syncthreads();
  if (tid < 48) op[tid] = scal[tid];
  if (tid == 0) {
    op[48] = tb0; op[49] = tb1; op[50] = tb2; op[51] = tb3; op[52] = tb4;
  }
  if (tid < 9) {
    op[3128 + tid] = ac[tid];
    op[3137 + tid] = (acmax != 0.f) ? ac[tid] / acmax : 0.f;
  }
}

extern "C" void kernel_launch(void* const* d_in, const int* in_sizes, int n_in,
                              void* d_out, int out_size, void* d_ws, size_t ws_size,
                              hipStream_t stream) {
  const float* x = (const float*)d_in[0];
  float* out = (float*)d_out;
  const int total = in_sizes[0];
  const int B = total / (T_LEN * NF);
  const int nblocks = B * NF;
  ts_feat_kernel<<<nblocks, NTH, 0, stream>>>(x, out);
}

// Round 2
// 340.308 us; speedup vs baseline: 2.5523x; 2.5523x over previous
//
#include <hip/hip_runtime.h>
#include <math.h>

#define T_LEN 2048
#define NF    16
#define NTH   256
#define NOUT  3146

// ---------------- wave reductions (wave = 64) ----------------
__device__ __forceinline__ float wred_sum(float v) {
  v += __shfl_down(v, 32);
  v += __shfl_down(v, 16);
  v += __shfl_down(v, 8);
  v += __shfl_down(v, 4);
  v += __shfl_down(v, 2);
  v += __shfl_down(v, 1);
  return v;
}
__device__ __forceinline__ float wred_min(float v) {
  v = fminf(v, __shfl_down(v, 32));
  v = fminf(v, __shfl_down(v, 16));
  v = fminf(v, __shfl_down(v, 8));
  v = fminf(v, __shfl_down(v, 4));
  v = fminf(v, __shfl_down(v, 2));
  v = fminf(v, __shfl_down(v, 1));
  return v;
}
__device__ __forceinline__ float wred_max(float v) {
  v = fmaxf(v, __shfl_down(v, 32));
  v = fmaxf(v, __shfl_down(v, 16));
  v = fmaxf(v, __shfl_down(v, 8));
  v = fmaxf(v, __shfl_down(v, 4));
  v = fmaxf(v, __shfl_down(v, 2));
  v = fmaxf(v, __shfl_down(v, 1));
  return v;
}

__device__ __forceinline__ float block_sum(float v, float* red, int tid) {
  v = wred_sum(v);
  if ((tid & 63) == 0) red[tid >> 6] = v;
  __syncthreads();
  if (tid == 0) red[4] = red[0] + red[1] + red[2] + red[3];
  __syncthreads();
  float r = red[4];
  __syncthreads();
  return r;
}
__device__ __forceinline__ float block_min(float v, float* red, int tid) {
  v = wred_min(v);
  if ((tid & 63) == 0) red[tid >> 6] = v;
  __syncthreads();
  if (tid == 0) red[4] = fminf(fminf(red[0], red[1]), fminf(red[2], red[3]));
  __syncthreads();
  float r = red[4];
  __syncthreads();
  return r;
}
__device__ __forceinline__ float block_max(float v, float* red, int tid) {
  v = wred_max(v);
  if ((tid & 63) == 0) red[tid >> 6] = v;
  __syncthreads();
  if (tid == 0) red[4] = fmaxf(fmaxf(red[0], red[1]), fmaxf(red[2], red[3]));
  __syncthreads();
  float r = red[4];
  __syncthreads();
  return r;
}

// batched block sum: N values, 2 barriers total
template<int N>
__device__ __forceinline__ void block_sum_n(float (&v)[N], float* redw, float* res, int tid) {
  const int wave = tid >> 6;
#pragma unroll
  for (int j = 0; j < N; j++) {
    float s = wred_sum(v[j]);
    if ((tid & 63) == 0) redw[j * 4 + wave] = s;
  }
  __syncthreads();
  if (tid < N) res[tid] = redw[tid * 4] + redw[tid * 4 + 1] + redw[tid * 4 + 2] + redw[tid * 4 + 3];
  __syncthreads();
}

// agg4 over 9 register values (fully unrolled, static indices)
__device__ __forceinline__ void agg4_9(const float* v, float* om, float* ov, float* os, float* ok) {
  const float fn = 9.0f;
  float s = 0.f;
#pragma unroll
  for (int i = 0; i < 9; i++) s += v[i];
  float m = s / fn;
  float c2 = 0.f, c3 = 0.f, c4 = 0.f;
#pragma unroll
  for (int i = 0; i < 9; i++) {
    float c = v[i] - m;
    float cc = c * c;
    c2 += cc; c3 += cc * c; c4 += cc * cc;
  }
  float var = c2 / fn;
  float sd = (var > 0.f) ? sqrtf(var) : 0.f;
  float sk = (sd > 0.f) ? fn / ((fn - 1.f) * (fn - 2.f)) * (c3 / (sd * sd * sd)) : 0.f;
  float k22 = c2 * c2;
  float al = fn * (fn + 1.f) * (fn - 1.f) / ((fn - 2.f) * (fn - 3.f));
  float ku = ((k22 > 0.f) ? al * c4 / k22 : 0.f)
             - 3.f * (fn - 1.f) * (fn - 1.f) / ((fn - 2.f) * (fn - 3.f));
  *om = m; *ov = var; *os = sk; *ok = ku;
}

// histogram scan: sums 4 per-wave hists (H[0..1023]) into inclusive cum at H[1024..1279]
__device__ __forceinline__ void hist_scan(unsigned int* H, int tid) {
  if (tid < 64) {
    const int l = tid;
    unsigned int b0 = H[4 * l]     + H[256 + 4 * l]     + H[512 + 4 * l]     + H[768 + 4 * l];
    unsigned int b1 = H[4 * l + 1] + H[256 + 4 * l + 1] + H[512 + 4 * l + 1] + H[768 + 4 * l + 1];
    unsigned int b2 = H[4 * l + 2] + H[256 + 4 * l + 2] + H[512 + 4 * l + 2] + H[768 + 4 * l + 2];
    unsigned int b3 = H[4 * l + 3] + H[256 + 4 * l + 3] + H[512 + 4 * l + 3] + H[768 + 4 * l + 3];
    unsigned int s0 = b0, s1 = s0 + b1, s2 = s1 + b2, s3 = s2 + b3;
    unsigned int tot = s3;
#pragma unroll
    for (int off = 1; off < 64; off <<= 1) {
      unsigned int n = __shfl_up(tot, off);
      if (l >= off) tot += n;
    }
    unsigned int base = tot - s3;
    H[1024 + 4 * l]     = base + s0;
    H[1024 + 4 * l + 1] = base + s1;
    H[1024 + 4 * l + 2] = base + s2;
    H[1024 + 4 * l + 3] = base + s3;
  }
  __syncthreads();
}

__device__ __forceinline__ float ord2f(unsigned int u) {
  unsigned int v = (u & 0x80000000u) ? (u ^ 0x80000000u) : ~u;
  return __uint_as_float(v);
}

__global__ __launch_bounds__(NTH)
void ts_feat_kernel(const float* __restrict__ x, float* __restrict__ out, int gpx) {
  __shared__ float a[T_LEN];    // series; later: twiddle table; later: amp
  __shared__ float sb[T_LEN];   // radix keys (uint); later: FFT real
  __shared__ float sc[T_LEN];   // histograms (uint); later: bitrev scratch + FFT imag
  __shared__ float redw[80];
  __shared__ float res[20];
  __shared__ float red[8];
  __shared__ float scal[48];
  __shared__ unsigned int selres[8];

  const int tid = threadIdx.x;
  int b, f;
  {
    int i = blockIdx.x;
    if (gpx > 0) { int xc = i & 7; int slot = i >> 3; b = xc * gpx + (slot >> 4); f = slot & 15; }
    else { b = i >> 4; f = i & 15; }
  }
  const float* xp = x + ((size_t)b * T_LEN) * NF + f;
  float* op = out + (size_t)(b * NF + f) * NOUT;

  unsigned int* sbu = (unsigned int*)sb;
  unsigned int* H = (unsigned int*)sc;
  const int woff = (tid >> 6) << 8;

  // ---- load + build order-preserving radix keys ----
  for (int t = tid; t < T_LEN; t += NTH) {
    float v = xp[(size_t)t * NF];
    a[t] = v;
    unsigned int u = __float_as_uint(v);
    sbu[t] = (u & 0x80000000u) ? ~u : (u | 0x80000000u);
  }
  __syncthreads();

  const float fT = (float)T_LEN;

  // ---- pass 1: raw sums, min/max ----
  {
    float v2[2] = {0.f, 0.f};
    float mn = 3.4e38f, mx = -3.4e38f;
    for (int t = tid; t < T_LEN; t += NTH) {
      float v = a[t];
      v2[0] += v; v2[1] += v * v;
      mn = fminf(mn, v); mx = fmaxf(mx, v);
    }
    block_sum_n<2>(v2, redw, res, tid);
    float S1 = res[0], S2v = res[1];
    float MN = block_min(mn, red, tid);
    float MX = block_max(mx, red, tid);
    scal[0] = 0.f; // placeholder (avoid unused warnings pattern)
    // stash in registers via shared? keep in locals below
    // (recompute below from named values)
    red[5] = S1; red[6] = S2v; // persist S1,S2 through later red usage? no — copy now:
    // NOTE: we simply keep them in locals:
    float mean = S1 / fT;
    float maxabs = fmaxf(-MN, MX);
    float rms = (S2v / fT > 0.f) ? sqrtf(S2v / fT) : 0.f;

    // ---- pass 2: central moments + diffs + autocorr lags (merged) ----
    float v15[15];
#pragma unroll
    for (int j = 0; j < 15; j++) v15[j] = 0.f;
    for (int t = tid; t < T_LEN; t += NTH) {
      float c = a[t] - mean;
      float cc = c * c;
      v15[0] += cc; v15[1] += cc * c; v15[2] += cc * cc;
      if (t < T_LEN - 2) {
        float d = a[t + 1] - a[t + 2];
        v15[3] += d; v15[4] += fabsf(d); v15[5] += d * d;
      }
#pragma unroll
      for (int l = 1; l <= 9; l++) {
        float cl = (t + l < T_LEN) ? (a[t + l] - mean) : 0.f;
        v15[5 + l] += c * cl;
      }
    }
    block_sum_n<15>(v15, redw, res, tid);
    float C2 = res[0], C3 = res[1], C4 = res[2];
    float SD = res[3], SAD = res[4], SDD = res[5];
    float acr0 = res[6], acr1 = res[7], acr2 = res[8], acr3 = res[9], acr4 = res[10];
    float acr5 = res[11], acr6 = res[12], acr7 = res[13], acr8 = res[14];

    float var = C2 / fT;
    float sd = (var > 0.f) ? sqrtf(var) : 0.f;
    float skw = (sd > 0.f) ? (fT / ((fT - 1.f) * (fT - 2.f))) * (C3 / (sd * sd * sd)) : 0.f;
    float k22 = C2 * C2;
    float alphaT = fT * (fT + 1.f) * (fT - 1.f) / ((fT - 2.f) * (fT - 3.f));
    float kurt = ((k22 > 0.f) ? alphaT * C4 / k22 : 0.f)
                 - 3.f * (fT - 1.f) * (fT - 1.f) / ((fT - 2.f) * (fT - 3.f));

    float ac[9];
    {
      float invvar = (var != 0.f) ? 1.f / var : 0.f;
      ac[0] = acr0 / (fT - 1.f) * invvar;
      ac[1] = acr1 / (fT - 2.f) * invvar;
      ac[2] = acr2 / (fT - 3.f) * invvar;
      ac[3] = acr3 / (fT - 4.f) * invvar;
      ac[4] = acr4 / (fT - 5.f) * invvar;
      ac[5] = acr5 / (fT - 6.f) * invvar;
      ac[6] = acr6 / (fT - 7.f) * invvar;
      ac[7] = acr7 / (fT - 8.f) * invvar;
      ac[8] = acr8 / (fT - 9.f) * invvar;
    }
    float acm, acv, acs, ack;
    agg4_9(ac, &acm, &acv, &acs, &ack);
    float acmax = ac[0];
#pragma unroll
    for (int l = 1; l < 9; l++) acmax = fmaxf(acmax, ac[l]);

    // ---- radix select: exact order statistics at ranks 512,1024,1536 ----
    unsigned int prefix[3] = {0u, 0u, 0u};
    unsigned int rank[3] = {512u, 1024u, 1536u};

    // round 1 (shift 24) shared across targets
    for (int q = tid; q < 1024; q += NTH) H[q] = 0u;
    __syncthreads();
    for (int t = tid; t < T_LEN; t += NTH) {
      unsigned int u = sbu[t];
      atomicAdd(&H[woff + (u >> 24)], 1u);
    }
    __syncthreads();
    hist_scan(H, tid);
    if (tid < 256) {
      unsigned int incl = H[1024 + tid];
      unsigned int excl = (tid == 0) ? 0u : H[1024 + tid - 1];
#pragma unroll
      for (int j = 0; j < 3; j++) {
        if (excl <= rank[j] && rank[j] < incl) { selres[2 * j] = (unsigned int)tid; selres[2 * j + 1] = rank[j] - excl; }
      }
    }
    __syncthreads();
#pragma unroll
    for (int j = 0; j < 3; j++) { prefix[j] = selres[2 * j] << 24; rank[j] = selres[2 * j + 1]; }

    // rounds 2..4 per target
    for (int rnd = 1; rnd < 4; rnd++) {
      const int shift = 24 - 8 * rnd;
#pragma unroll
      for (int j = 0; j < 3; j++) {
        __syncthreads();
        for (int q = tid; q < 1024; q += NTH) H[q] = 0u;
        __syncthreads();
        const unsigned int ph = prefix[j] >> (shift + 8);
        for (int t = tid; t < T_LEN; t += NTH) {
          unsigned int u = sbu[t];
          if ((u >> (shift + 8)) == ph)
            atomicAdd(&H[woff + ((u >> shift) & 255u)], 1u);
        }
        __syncthreads();
        hist_scan(H, tid);
        if (tid < 256) {
          unsigned int incl = H[1024 + tid];
          unsigned int excl = (tid == 0) ? 0u : H[1024 + tid - 1];
          if (excl <= rank[j] && rank[j] < incl) { selres[0] = (unsigned int)tid; selres[1] = rank[j] - excl; }
        }
        __syncthreads();
        prefix[j] |= selres[0] << shift;
        rank[j] = selres[1];
      }
    }
    __syncthreads();

    float q0 = ord2f(prefix[0]);
    float q1 = ord2f(prefix[1]);
    float q2 = ord2f(prefix[2]);
    float tb0 = a[0], tb1 = a[512], tb2 = a[1024], tb3 = a[1536], tb4 = a[2047];

    // ---- pass 4: count_above + crossings for 10 thresholds ----
    float thrv0 = 0.f, thrv1 = mean, thrv2 = q0, thrv3 = q1, thrv4 = q2;
    float thrv5 = tb0, thrv6 = tb1, thrv7 = tb2, thrv8 = tb3, thrv9 = tb4;
    float v20[20];
#pragma unroll
    for (int j = 0; j < 20; j++) v20[j] = 0.f;
    for (int t = tid; t < T_LEN; t += NTH) {
      float v = a[t];
      bool has_next = (t < T_LEN - 1);
      float vn = has_next ? a[t + 1] : 0.f;
#define DO_THR(J, THR)                                   \
      {                                                  \
        float d = v - (THR);                             \
        int s = (d > 0.f) - (d < 0.f);                   \
        v20[J] += (s == 1) ? 1.f : 0.f;                  \
        if (has_next) {                                  \
          float dn = vn - (THR);                         \
          int sn = (dn > 0.f) - (dn < 0.f);              \
          v20[10 + J] += (s != sn) ? 1.f : 0.f;          \
        }                                                \
      }
      DO_THR(0, thrv0) DO_THR(1, thrv1) DO_THR(2, thrv2) DO_THR(3, thrv3) DO_THR(4, thrv4)
      DO_THR(5, thrv5) DO_THR(6, thrv6) DO_THR(7, thrv7) DO_THR(8, thrv8) DO_THR(9, thrv9)
#undef DO_THR
    }
    block_sum_n<20>(v20, redw, res, tid);
    float CNT0 = res[0], CNT1 = res[1], CNT2 = res[2], CNT3 = res[3], CNT4 = res[4];
    float CNT5 = res[5], CNT6 = res[6], CNT7 = res[7], CNT8 = res[8], CNT9 = res[9];
    float CRS0 = res[10], CRS1 = res[11], CRS2 = res[12], CRS3 = res[13], CRS4 = res[14];
    float CRS5 = res[15], CRS6 = res[16], CRS7 = res[17], CRS8 = res[18], CRS9 = res[19];
    (void)CNT2; (void)CNT3; (void)CNT4;

    // ---- FFT prep: conflict-free bit-reversal through sc + twiddle table in a ----
    // step 1: scramble a into sc with XOR-swizzled layout
    for (int t = tid; t < T_LEN; t += NTH) {
      int lo = t & 63, hi = t >> 6;
      int rl = (int)(__brev((unsigned int)lo) >> 26);
      sc[rl * 32 + (hi ^ (rl & 31))] = a[t];
    }
    __syncthreads();
    // step 2: unscramble into sb (bit-reversed order); build twiddle table in a (a now dead)
    for (int r = tid; r < T_LEN; r += NTH) {
      int j2 = r >> 5, k = r & 31;
      int rk = (int)(__brev((unsigned int)k) >> 27);
      sb[r] = sc[j2 * 32 + (rk ^ (j2 & 31))];
    }
    for (int p = tid; p < 1024; p += NTH) {
      float sn, cs;
      sincosf(-3.14159265358979323846f / 1024.f * (float)p, &sn, &cs);
      int q = p ^ (p >> 5);
      a[q] = cs;
      a[1024 + q] = sn;
    }
    __syncthreads();

    // stage 1 (twiddle = 1, imag input = 0): fuse imag zeroing
    for (int m = tid; m < 1024; m += NTH) {
      int i0 = m << 1, i1 = i0 | 1;
      float ur = sb[i0], xr = sb[i1];
      sb[i0] = ur + xr; sb[i1] = ur - xr;
      sc[i0] = 0.f; sc[i1] = 0.f;
    }
    // stages 2..11 with table twiddles
    for (int s = 2; s <= 11; s++) {
      const int hf = 1 << (s - 1);
      const int tsh = 11 - s;
      __syncthreads();
      for (int m = tid; m < 1024; m += NTH) {
        int pos = m & (hf - 1);
        int i0 = ((m >> (s - 1)) << s) | pos;
        int i1 = i0 + hf;
        int p = pos << tsh;
        int tix = p ^ (p >> 5);
        float cs = a[tix], sn = a[1024 + tix];
        float xr = sb[i1], xi = sc[i1];
        float tr = cs * xr - sn * xi;
        float ti2 = cs * xi + sn * xr;
        float ur = sb[i0], ui = sc[i0];
        sb[i0] = ur + tr; sc[i0] = ui + ti2;
        sb[i1] = ur - tr; sc[i1] = ui - ti2;
      }
    }
    __syncthreads();

    // ---- amp / ang; amp stored into a[0..1024] (table dead) ----
    float samp = 0.f;
    for (int k = tid; k <= T_LEN / 2; k += NTH) {
      float re = sb[k], im = sc[k];
      float amp = sqrtf(re * re + im * im);
      float ang = atan2f(im, re);
      op[53 + k] = amp;
      op[1078 + k] = ang;
      a[k] = amp;
      samp += amp;
    }
    __syncthreads();
    float S = block_sum(samp, red, tid);
    float invS = (S != 0.f) ? 1.f / S : 0.f;

    for (int k = tid; k <= T_LEN / 2; k += NTH) {
      op[2103 + k] = a[k] * invS;
    }

    // ---- agg4 over amp (n = 1025) ----
    const float fn = 1025.f;
    float am = S / fn;
    float v3[3] = {0.f, 0.f, 0.f};
    for (int k = tid; k <= T_LEN / 2; k += NTH) {
      float c = a[k] - am;
      float cc = c * c;
      v3[0] += cc; v3[1] += cc * c; v3[2] += cc * cc;
    }
    block_sum_n<3>(v3, redw, res, tid);
    float A2 = res[0], A3 = res[1], A4 = res[2];
    float av = A2 / fn;
    float asd = (av > 0.f) ? sqrtf(av) : 0.f;
    float ask = (asd > 0.f) ? fn / ((fn - 1.f) * (fn - 2.f)) * (A3 / (asd * asd * asd)) : 0.f;
    float ak22 = A2 * A2;
    float aal = fn * (fn + 1.f) * (fn - 1.f) / ((fn - 2.f) * (fn - 3.f));
    float aku = ((ak22 > 0.f) ? aal * A4 / ak22 : 0.f)
                - 3.f * (fn - 1.f) * (fn - 1.f) / ((fn - 2.f) * (fn - 3.f));
    float rm = am * invS;
    float rv = av * invS * invS;

    // ---- write scalars ----
    if (tid == 0) {
      scal[0] = mean; scal[1] = MN; scal[2] = MX; scal[3] = rms; scal[4] = var; scal[5] = sd;
      scal[6] = skw; scal[7] = kurt;
      scal[8] = SD / (fT - 2.f); scal[9] = SD; scal[10] = SAD / (fT - 2.f);
      scal[11] = S2v; scal[12] = maxabs; scal[13] = SAD;
      scal[14] = (SDD > 0.f) ? sqrtf(SDD) : 0.f;
      scal[15] = CNT0; scal[16] = CNT1;
      scal[17] = CNT5; scal[18] = CNT6; scal[19] = CNT7; scal[20] = CNT8; scal[21] = CNT9;
      scal[22] = CRS0; scal[23] = CRS1;
      scal[24] = CRS2; scal[25] = CRS3; scal[26] = CRS4;
      scal[27] = CRS5; scal[28] = CRS6; scal[29] = CRS7; scal[30] = CRS8; scal[31] = CRS9;
      scal[32] = a[0];  // amp[0]
      scal[33] = am; scal[34] = av; scal[35] = ask; scal[36] = aku;
      scal[37] = rm; scal[38] = rv; scal[39] = ask; scal[40] = aku;
      scal[41] = acm; scal[42] = acv; scal[43] = acs; scal[44] = ack;
      scal[45] = q0; scal[46] = q1; scal[47] = q2;
    }
    __syncthreads();
    if (tid < 48) op[tid] = scal[tid];
    if (tid == 0) {
      op[48] = tb0; op[49] = tb1; op[50] = tb2; op[51] = tb3; op[52] = tb4;
    }
    if (tid < 9) {
      float acj;
      switch (tid) {
        case 0: acj = ac[0]; break; case 1: acj = ac[1]; break; case 2: acj = ac[2]; break;
        case 3: acj = ac[3]; break; case 4: acj = ac[4]; break; case 5: acj = ac[5]; break;
        case 6: acj = ac[6]; break; case 7: acj = ac[7]; break; default: acj = ac[8]; break;
      }
      op[3128 + tid] = acj;
      op[3137 + tid] = (acmax != 0.f) ? acj / acmax : 0.f;
    }
  }
}

extern "C" void kernel_launch(void* const* d_in, const int* in_sizes, int n_in,
                              void* d_out, int out_size, void* d_ws, size_t ws_size,
                              hipStream_t stream) {
  const float* x = (const float*)d_in[0];
  float* out = (float*)d_out;
  const int total = in_sizes[0];
  const int B = total / (T_LEN * NF);
  const int nblocks = B * NF;
  const int gpx = (B % 8 == 0) ? (B / 8) : 0;
  ts_feat_kernel<<<nblocks, NTH, 0, stream>>>(x, out, gpx);
}

// Round 3
// 243.747 us; speedup vs baseline: 3.5634x; 1.3962x over previous
//
#include <hip/hip_runtime.h>
#include <math.h>

#define T_LEN 2048
#define NF    16
#define NTH   256
#define NOUT  3146
#define PI_F  3.14159265358979323846f

// ---------------- wave reductions (wave = 64) ----------------
__device__ __forceinline__ float wred_sum(float v) {
  v += __shfl_down(v, 32); v += __shfl_down(v, 16); v += __shfl_down(v, 8);
  v += __shfl_down(v, 4);  v += __shfl_down(v, 2);  v += __shfl_down(v, 1);
  return v;
}
__device__ __forceinline__ float wred_min(float v) {
  v = fminf(v, __shfl_down(v, 32)); v = fminf(v, __shfl_down(v, 16)); v = fminf(v, __shfl_down(v, 8));
  v = fminf(v, __shfl_down(v, 4));  v = fminf(v, __shfl_down(v, 2));  v = fminf(v, __shfl_down(v, 1));
  return v;
}
__device__ __forceinline__ float wred_max(float v) {
  v = fmaxf(v, __shfl_down(v, 32)); v = fmaxf(v, __shfl_down(v, 16)); v = fmaxf(v, __shfl_down(v, 8));
  v = fmaxf(v, __shfl_down(v, 4));  v = fmaxf(v, __shfl_down(v, 2));  v = fmaxf(v, __shfl_down(v, 1));
  return v;
}

// batched block sum: N values, 2 barriers total
template<int N>
__device__ __forceinline__ void block_sum_n(float (&v)[N], float* redw, float* res, int tid) {
  const int wave = tid >> 6;
#pragma unroll
  for (int j = 0; j < N; j++) {
    float s = wred_sum(v[j]);
    if ((tid & 63) == 0) redw[j * 4 + wave] = s;
  }
  __syncthreads();
  if (tid < N) res[tid] = redw[tid * 4] + redw[tid * 4 + 1] + redw[tid * 4 + 2] + redw[tid * 4 + 3];
  __syncthreads();
}

// agg4 over 9 register values
__device__ __forceinline__ void agg4_9(const float* v, float* om, float* ov, float* os, float* ok) {
  const float fn = 9.0f;
  float s = 0.f;
#pragma unroll
  for (int i = 0; i < 9; i++) s += v[i];
  float m = s / fn;
  float c2 = 0.f, c3 = 0.f, c4 = 0.f;
#pragma unroll
  for (int i = 0; i < 9; i++) {
    float c = v[i] - m; float cc = c * c;
    c2 += cc; c3 += cc * c; c4 += cc * cc;
  }
  float var = c2 / fn;
  float sd = (var > 0.f) ? sqrtf(var) : 0.f;
  float sk = (sd > 0.f) ? fn / ((fn - 1.f) * (fn - 2.f)) * (c3 / (sd * sd * sd)) : 0.f;
  float k22 = c2 * c2;
  float al = fn * (fn + 1.f) * (fn - 1.f) / ((fn - 2.f) * (fn - 3.f));
  float ku = ((k22 > 0.f) ? al * c4 / k22 : 0.f)
             - 3.f * (fn - 1.f) * (fn - 1.f) / ((fn - 2.f) * (fn - 3.f));
  *om = m; *ov = var; *os = sk; *ok = ku;
}

// round-A scan: 4 per-wave hists at U[0..1023] -> inclusive cum at U[1024..1279]
__device__ __forceinline__ void hist_scan(unsigned int* U, int tid) {
  if (tid < 64) {
    const int l = tid;
    unsigned int b0 = U[4*l]   + U[256+4*l]   + U[512+4*l]   + U[768+4*l];
    unsigned int b1 = U[4*l+1] + U[256+4*l+1] + U[512+4*l+1] + U[768+4*l+1];
    unsigned int b2 = U[4*l+2] + U[256+4*l+2] + U[512+4*l+2] + U[768+4*l+2];
    unsigned int b3 = U[4*l+3] + U[256+4*l+3] + U[512+4*l+3] + U[768+4*l+3];
    unsigned int s0 = b0, s1 = s0+b1, s2 = s1+b2, s3 = s2+b3;
    unsigned int tot = s3;
#pragma unroll
    for (int off = 1; off < 64; off <<= 1) {
      unsigned int n = __shfl_up(tot, off);
      if (l >= off) tot += n;
    }
    unsigned int base = tot - s3;
    U[1024+4*l] = base+s0; U[1024+4*l+1] = base+s1; U[1024+4*l+2] = base+s2; U[1024+4*l+3] = base+s3;
  }
  __syncthreads();
}

// rounds B-D scan: 3 target hists at U[j*256..], cums at U[768+j*256..]
__device__ __forceinline__ void hist_scan3(unsigned int* U, int tid) {
  if (tid < 192) {
    int w = tid >> 6, l = tid & 63;
    unsigned int* h = U + w * 256;
    unsigned int b0 = h[4*l], b1 = h[4*l+1], b2 = h[4*l+2], b3 = h[4*l+3];
    unsigned int s0 = b0, s1 = s0+b1, s2 = s1+b2, s3 = s2+b3;
    unsigned int tot = s3;
#pragma unroll
    for (int off = 1; off < 64; off <<= 1) {
      unsigned int n = __shfl_up(tot, off);
      if (l >= off) tot += n;
    }
    unsigned int base = tot - s3;
    unsigned int* c = U + 768 + w * 256;
    c[4*l] = base+s0; c[4*l+1] = base+s1; c[4*l+2] = base+s2; c[4*l+3] = base+s3;
  }
  __syncthreads();
}

__device__ __forceinline__ float ord2f(unsigned int u) {
  unsigned int v = (u & 0x80000000u) ? (u ^ 0x80000000u) : ~u;
  return __uint_as_float(v);
}

// fast atan2 (poly, max err ~1e-4 rad; output threshold is 50.24 absolute)
__device__ __forceinline__ float fast_atan2f(float y, float x) {
  float ay = fabsf(y), ax = fabsf(x);
  float mx = fmaxf(ax, ay), mn = fminf(ax, ay);
  if (mx == 0.f) return 0.f;
  float t = __fdividef(mn, mx);
  float s = t * t;
  float p = fmaf(s, fmaf(s, fmaf(s, fmaf(s, 0.0208351f, -0.0851330f), 0.1801410f), -0.3302995f), 0.9998660f);
  float r = t * p;
  if (ay > ax) r = 1.57079632679f - r;
  if (x < 0.f) r = PI_F - r;
  return (y < 0.f) ? -r : r;
}

__global__ __launch_bounds__(NTH)
void ts_feat_kernel(const float* __restrict__ x, float* __restrict__ out, int gpx) {
  __shared__ __align__(16) float a[T_LEN];        // series; later amp[0..1024]
  __shared__ __align__(16) float zr[1024];        // FFT real (packed)
  __shared__ __align__(16) float zi[1024];        // FFT imag (packed)
  __shared__ __align__(16) unsigned int U[1536];  // radix hists/cums; later twiddle table
  __shared__ float redw[80];
  __shared__ float res[24];
  __shared__ float scal[48];
  __shared__ unsigned int selres[8];

  const int tid = threadIdx.x;
  int b, f;
  {
    int i = blockIdx.x;
    if (gpx > 0) { int xc = i & 7; int slot = i >> 3; b = xc * gpx + (slot >> 4); f = slot & 15; }
    else { b = i >> 4; f = i & 15; }
  }
  const float* xp = x + ((size_t)b * T_LEN) * NF + f;
  float* op = out + (size_t)(b * NF + f) * NOUT;
  const float fT = (float)T_LEN;

  // ---- phase 1: load + raw stats ----
  float mean, S2v, MN, MX;
  {
    float s1 = 0.f, s2 = 0.f, mn = 3.4e38f, mx = -3.4e38f;
#pragma unroll
    for (int k = 0; k < 8; k++) {
      int t = tid + k * NTH;
      float v = xp[(size_t)t * NF];
      a[t] = v;
      s1 += v; s2 += v * v; mn = fminf(mn, v); mx = fmaxf(mx, v);
    }
    s1 = wred_sum(s1); s2 = wred_sum(s2); mn = wred_min(mn); mx = wred_max(mx);
    if ((tid & 63) == 0) { int w = tid >> 6; redw[w] = s1; redw[4+w] = s2; redw[8+w] = mn; redw[12+w] = mx; }
    __syncthreads();
    if (tid == 0) {
      res[0] = redw[0]+redw[1]+redw[2]+redw[3];
      res[1] = redw[4]+redw[5]+redw[6]+redw[7];
      res[2] = fminf(fminf(redw[8], redw[9]), fminf(redw[10], redw[11]));
      res[3] = fmaxf(fmaxf(redw[12], redw[13]), fmaxf(redw[14], redw[15]));
    }
    __syncthreads();
    mean = res[0] / fT; S2v = res[1]; MN = res[2]; MX = res[3];
  }
  float maxabs = fmaxf(-MN, MX);
  float rms = sqrtf(fmaxf(S2v / fT, 0.f));

  // ---- phase 2: central moments + diffs + autocorr (consecutive chunks, b128 reads) ----
  float var, sd, skw, kurt, SD, SAD, SDD;
  float ac[9], acm, acv, acs, ack, acmax;
  {
    const int base = tid * 8;
    const float4* a4 = (const float4*)a;
    float4 w0 = a4[tid*2], w1 = a4[tid*2+1];
    int i2 = (base + 11 < T_LEN) ? tid*2+2 : 0;
    int i3 = (base + 15 < T_LEN) ? tid*2+3 : 0;
    float4 w2 = a4[i2], w3 = a4[i3];
    bool ok2 = (base + 11 < T_LEN), ok3 = (base + 15 < T_LEN);
    float r[17];
    r[0]=w0.x; r[1]=w0.y; r[2]=w0.z; r[3]=w0.w;
    r[4]=w1.x; r[5]=w1.y; r[6]=w1.z; r[7]=w1.w;
    r[8]  = ok2 ? w2.x : mean; r[9]  = ok2 ? w2.y : mean; r[10] = ok2 ? w2.z : mean; r[11] = ok2 ? w2.w : mean;
    r[12] = ok3 ? w3.x : mean; r[13] = ok3 ? w3.y : mean; r[14] = ok3 ? w3.z : mean; r[15] = ok3 ? w3.w : mean;
    r[16] = (base + 16 < T_LEN) ? a[base + 16] : mean;

    float v15[15];
#pragma unroll
    for (int j = 0; j < 15; j++) v15[j] = 0.f;
#pragma unroll
    for (int j = 0; j < 8; j++) {
      float c = r[j] - mean; float cc = c * c;
      v15[0] += cc; v15[1] += cc * c; v15[2] += cc * cc;
    }
#pragma unroll
    for (int j = 0; j < 8; j++) {
      if (base + j < T_LEN - 2) {
        float d = r[j+1] - r[j+2];
        v15[3] += d; v15[4] += fabsf(d); v15[5] += d * d;
      }
    }
#pragma unroll
    for (int l = 1; l <= 9; l++) {
#pragma unroll
      for (int j = 0; j < 8; j++) {
        v15[5 + l] += (r[j] - mean) * (r[j + l] - mean);  // OOB r == mean -> 0
      }
    }
    block_sum_n<15>(v15, redw, res, tid);
    float C2 = res[0], C3 = res[1], C4 = res[2];
    SD = res[3]; SAD = res[4]; SDD = res[5];
    var = C2 / fT;
    sd = (var > 0.f) ? sqrtf(var) : 0.f;
    skw = (sd > 0.f) ? (fT / ((fT - 1.f) * (fT - 2.f))) * (C3 / (sd * sd * sd)) : 0.f;
    float k22 = C2 * C2;
    float alphaT = fT * (fT + 1.f) * (fT - 1.f) / ((fT - 2.f) * (fT - 3.f));
    kurt = ((k22 > 0.f) ? alphaT * C4 / k22 : 0.f)
           - 3.f * (fT - 1.f) * (fT - 1.f) / ((fT - 2.f) * (fT - 3.f));
    float invvar = (var != 0.f) ? 1.f / var : 0.f;
#pragma unroll
    for (int l = 1; l <= 9; l++) ac[l-1] = res[5 + l] / (fT - (float)l) * invvar;
    agg4_9(ac, &acm, &acv, &acs, &ack);
    acmax = ac[0];
#pragma unroll
    for (int l = 1; l < 9; l++) acmax = fmaxf(acmax, ac[l]);
  }

  // ---- phase 3: radix select (keys in registers, 4 scan passes) ----
  float q0, q1, q2;
  {
    unsigned int key[8];
#pragma unroll
    for (int k = 0; k < 8; k++) {
      unsigned int u = __float_as_uint(a[tid + k * NTH]);
      key[k] = (u & 0x80000000u) ? ~u : (u | 0x80000000u);
    }
    unsigned int prefix[3] = {0u, 0u, 0u};
    unsigned int rank[3] = {512u, 1024u, 1536u};
    const int woff = (tid >> 6) << 8;

    // round A: top byte, per-wave hists
    for (int q = tid; q < 1280; q += NTH) U[q] = 0u;
    __syncthreads();
#pragma unroll
    for (int k = 0; k < 8; k++) atomicAdd(&U[woff + (key[k] >> 24)], 1u);
    __syncthreads();
    hist_scan(U, tid);
    if (tid < 256) {
      unsigned int incl = U[1024 + tid];
      unsigned int excl = (tid == 0) ? 0u : U[1024 + tid - 1];
#pragma unroll
      for (int j = 0; j < 3; j++)
        if (excl <= rank[j] && rank[j] < incl) { selres[2*j] = (unsigned)tid; selres[2*j+1] = rank[j] - excl; }
    }
    __syncthreads();
#pragma unroll
    for (int j = 0; j < 3; j++) { prefix[j] = selres[2*j] << 24; rank[j] = selres[2*j+1]; }
    __syncthreads();

    // rounds B..D: 3 targets concurrently, shared hists
    for (int rnd = 1; rnd < 4; rnd++) {
      const int shift = 24 - 8 * rnd;
      for (int q = tid; q < 1536; q += NTH) U[q] = 0u;
      __syncthreads();
#pragma unroll
      for (int k = 0; k < 8; k++) {
        unsigned int u = key[k];
        unsigned int hi = u >> (shift + 8);
#pragma unroll
        for (int j = 0; j < 3; j++) {
          if (hi == (prefix[j] >> (shift + 8)))
            atomicAdd(&U[j * 256 + ((u >> shift) & 255u)], 1u);
        }
      }
      __syncthreads();
      hist_scan3(U, tid);
      if (tid < 192) {
        int j = tid >> 6, l = tid & 63;
#pragma unroll
        for (int i = 0; i < 4; i++) {
          int bk = 4 * l + i;
          unsigned int incl = U[768 + j * 256 + bk];
          unsigned int excl = (bk == 0) ? 0u : U[768 + j * 256 + bk - 1];
          if (excl <= rank[j] && rank[j] < incl) { selres[2*j] = (unsigned)bk; selres[2*j+1] = rank[j] - excl; }
        }
      }
      __syncthreads();
#pragma unroll
      for (int j = 0; j < 3; j++) { prefix[j] |= selres[2*j] << shift; rank[j] = selres[2*j+1]; }
      if (rnd < 3) __syncthreads();
    }
    q0 = ord2f(prefix[0]); q1 = ord2f(prefix[1]); q2 = ord2f(prefix[2]);
  }

  float tb0 = a[0], tb1 = a[512], tb2 = a[1024], tb3 = a[1536], tb4 = a[2047];

  // ---- phase 4: count_above + crossings (consecutive chunks) ----
  float CNT0, CNT1, CNT5, CNT6, CNT7, CNT8, CNT9;
  float CRS0, CRS1, CRS2, CRS3, CRS4, CRS5, CRS6, CRS7, CRS8, CRS9;
  {
    const int base = tid * 8;
    const float4* a4 = (const float4*)a;
    float4 w0 = a4[tid*2], w1 = a4[tid*2+1];
    float rr[9];
    rr[0]=w0.x; rr[1]=w0.y; rr[2]=w0.z; rr[3]=w0.w;
    rr[4]=w1.x; rr[5]=w1.y; rr[6]=w1.z; rr[7]=w1.w;
    rr[8] = (base + 8 < T_LEN) ? a[base + 8] : 0.f;
    float v20[20];
#pragma unroll
    for (int j = 0; j < 20; j++) v20[j] = 0.f;
#pragma unroll
    for (int j = 0; j < 8; j++) {
      float v = rr[j], vn = rr[j + 1];
      bool hn = (base + j) < (T_LEN - 1);
#define THR_ONE(J, TH)                                            \
      { float d = v - (TH); int s = (d > 0.f) - (d < 0.f);        \
        v20[J] += (s == 1) ? 1.f : 0.f;                           \
        if (hn) { float dn = vn - (TH); int sn = (dn > 0.f) - (dn < 0.f); \
          v20[10 + J] += (s != sn) ? 1.f : 0.f; } }
      THR_ONE(0, 0.f)  THR_ONE(1, mean) THR_ONE(2, q0)  THR_ONE(3, q1)  THR_ONE(4, q2)
      THR_ONE(5, tb0)  THR_ONE(6, tb1)  THR_ONE(7, tb2) THR_ONE(8, tb3) THR_ONE(9, tb4)
#undef THR_ONE
    }
    block_sum_n<20>(v20, redw, res, tid);
    CNT0 = res[0]; CNT1 = res[1];
    CNT5 = res[5]; CNT6 = res[6]; CNT7 = res[7]; CNT8 = res[8]; CNT9 = res[9];
    CRS0 = res[10]; CRS1 = res[11]; CRS2 = res[12]; CRS3 = res[13]; CRS4 = res[14];
    CRS5 = res[15]; CRS6 = res[16]; CRS7 = res[17]; CRS8 = res[18]; CRS9 = res[19];
  }

  // ---- phase 5: packed real FFT (1024-pt complex) + untangle + amp/ang ----
  float amp0, amp1, amp2, amp3, amp4 = 0.f, S, invS;
  {
    float* Uf = (float*)U;  // twiddle table: cos at [0..511], sin at [512..1023]
#pragma unroll
    for (int k = 0; k < 2; k++) {
      int p = tid + k * NTH;
      float sn, cs;
      __sincosf(-PI_F / 512.f * (float)p, &sn, &cs);
      int qx = p ^ (p >> 5);
      Uf[qx] = cs; Uf[512 + qx] = sn;
    }
    // step 1: scramble pairs into zr/zi (conflict-free two-step bitrev, part 1)
    const float2* a2 = (const float2*)a;
#pragma unroll
    for (int k = 0; k < 4; k++) {
      int p = tid + k * NTH;
      float2 z = a2[p];
      int rl = (int)(__brev((unsigned)(p & 31)) >> 27);
      int c = p >> 5;
      int idx = rl * 32 + (c ^ rl);
      zr[idx] = z.x; zi[idx] = z.y;
    }
    __syncthreads();
    // step 2: gather bit-reversed into regs, write natural order
    float gr[4], gi[4];
#pragma unroll
    for (int k = 0; k < 4; k++) {
      int m = tid + k * NTH;
      int h = m >> 5, l = m & 31;
      int rl5 = (int)(__brev((unsigned)l) >> 27);
      int idx = h * 32 + (rl5 ^ h);
      gr[k] = zr[idx]; gi[k] = zi[idx];
    }
    __syncthreads();
#pragma unroll
    for (int k = 0; k < 4; k++) { int m = tid + k * NTH; zr[m] = gr[k]; zi[m] = gi[k]; }
    // 10 stages, 512 butterflies each (2 per thread)
    for (int s = 1; s <= 10; s++) {
      const int hf = 1 << (s - 1);
      const int tsh = 10 - s;
      __syncthreads();
#pragma unroll
      for (int jj = 0; jj < 2; jj++) {
        int m = tid + (jj << 8);
        int pos = m & (hf - 1);
        int i0 = ((m >> (s - 1)) << s) | pos;
        int i1 = i0 + hf;
        int p = pos << tsh;
        int tix = p ^ (p >> 5);
        float cs = Uf[tix], sn = Uf[512 + tix];
        float xr = zr[i1], xi = zi[i1];
        float tr = cs * xr - sn * xi;
        float ti = cs * xi + sn * xr;
        float ur = zr[i0], ui = zi[i0];
        zr[i0] = ur + tr; zi[i0] = ui + ti;
        zr[i1] = ur - tr; zi[i1] = ui - ti;
      }
    }
    __syncthreads();

    // untangle to rfft bins k=0..1024, fused amp/ang
    float samp = 0.f;
    float ampv[4];
#pragma unroll
    for (int k = 0; k < 4; k++) {
      int kk = tid + k * NTH;
      int nk = (1024 - kk) & 1023;
      float z1r = zr[kk], z1i = zi[kk];
      float z2r = zr[nk], z2i = zi[nk];
      float Er = 0.5f * (z1r + z2r), Ei = 0.5f * (z1i - z2i);
      float Or = 0.5f * (z1i + z2i), Oi = -0.5f * (z1r - z2r);
      float sn, cs;
      __sincosf(-PI_F * (float)kk * (1.f / 1024.f), &sn, &cs);
      float Xr = Er + cs * Or - sn * Oi;
      float Xi = Ei + cs * Oi + sn * Or;
      float amp = sqrtf(Xr * Xr + Xi * Xi);
      float ang = fast_atan2f(Xi, Xr);
      op[53 + kk] = amp;
      op[1078 + kk] = ang;
      a[kk] = amp;
      samp += amp;
      ampv[k] = amp;
    }
    amp0 = ampv[0]; amp1 = ampv[1]; amp2 = ampv[2]; amp3 = ampv[3];
    if (tid == 0) {  // k = 1024 (Nyquist): X = E0 - O0 = zr[0] - zi[0], imag 0
      float Xr = zr[0] - zi[0];
      float amp = fabsf(Xr);
      op[53 + 1024] = amp;
      op[1078 + 1024] = (Xr < 0.f) ? PI_F : 0.f;
      a[1024] = amp;
      samp += amp;
      amp4 = amp;
    }
    float v1[1] = {samp};
    block_sum_n<1>(v1, redw, res, tid);
    S = res[0];
    invS = (S != 0.f) ? 1.f / S : 0.f;
    op[2103 + tid]       = amp0 * invS;
    op[2103 + tid + 256] = amp1 * invS;
    op[2103 + tid + 512] = amp2 * invS;
    op[2103 + tid + 768] = amp3 * invS;
    if (tid == 0) op[2103 + 1024] = amp4 * invS;
  }

  // ---- phase 6: agg4 over amp (n = 1025), from registers ----
  const float fn = 1025.f;
  float am = S / fn;
  float av, ask, aku, rm, rv;
  {
    float c0 = amp0 - am, c1 = amp1 - am, c2 = amp2 - am, c3 = amp3 - am;
    float c4 = (tid == 0) ? (amp4 - am) : 0.f;
    float v3[3];
    v3[0] = c0*c0 + c1*c1 + c2*c2 + c3*c3 + c4*c4;
    v3[1] = c0*c0*c0 + c1*c1*c1 + c2*c2*c2 + c3*c3*c3 + c4*c4*c4;
    v3[2] = c0*c0*c0*c0 + c1*c1*c1*c1 + c2*c2*c2*c2 + c3*c3*c3*c3 + c4*c4*c4*c4;
    block_sum_n<3>(v3, redw, res, tid);
    float A2 = res[0], A3 = res[1], A4 = res[2];
    av = A2 / fn;
    float asd = (av > 0.f) ? sqrtf(av) : 0.f;
    ask = (asd > 0.f) ? fn / ((fn - 1.f) * (fn - 2.f)) * (A3 / (asd * asd * asd)) : 0.f;
    float ak22 = A2 * A2;
    float aal = fn * (fn + 1.f) * (fn - 1.f) / ((fn - 2.f) * (fn - 3.f));
    aku = ((ak22 > 0.f) ? aal * A4 / ak22 : 0.f)
          - 3.f * (fn - 1.f) * (fn - 1.f) / ((fn - 2.f) * (fn - 3.f));
    rm = am * invS;
    rv = av * invS * invS;
  }

  // ---- write scalars ----
  if (tid == 0) {
    scal[0] = mean; scal[1] = MN; scal[2] = MX; scal[3] = rms; scal[4] = var; scal[5] = sd;
    scal[6] = skw; scal[7] = kurt;
    scal[8] = SD / (fT - 2.f); scal[9] = SD; scal[10] = SAD / (fT - 2.f);
    scal[11] = S2v; scal[12] = maxabs; scal[13] = SAD;
    scal[14] = (SDD > 0.f) ? sqrtf(SDD) : 0.f;
    scal[15] = CNT0; scal[16] = CNT1;
    scal[17] = CNT5; scal[18] = CNT6; scal[19] = CNT7; scal[20] = CNT8; scal[21] = CNT9;
    scal[22] = CRS0; scal[23] = CRS1;
    scal[24] = CRS2; scal[25] = CRS3; scal[26] = CRS4;
    scal[27] = CRS5; scal[28] = CRS6; scal[29] = CRS7; scal[30] = CRS8; scal[31] = CRS9;
    scal[32] = a[0];  // amp[0]
    scal[33] = am; scal[34] = av; scal[35] = ask; scal[36] = aku;
    scal[37] = rm; scal[38] = rv; scal[39] = ask; scal[40] = aku;
    scal[41] = acm; scal[42] = acv; scal[43] = acs; scal[44] = ack;
    scal[45] = q0; scal[46] = q1; scal[47] = q2;
  }
  __syncthreads();
  if (tid < 48) op[tid] = scal[tid];
  if (tid == 0) {
    op[48] = tb0; op[49] = tb1; op[50] = tb2; op[51] = tb3; op[52] = tb4;
  }
  if (tid < 9) {
    float acj;
    switch (tid) {
      case 0: acj = ac[0]; break; case 1: acj = ac[1]; break; case 2: acj = ac[2]; break;
      case 3: acj = ac[3]; break; case 4: acj = ac[4]; break; case 5: acj = ac[5]; break;
      case 6: acj = ac[6]; break; case 7: acj = ac[7]; break; default: acj = ac[8]; break;
    }
    op[3128 + tid] = acj;
    op[3137 + tid] = (acmax != 0.f) ? acj / acmax : 0.f;
  }
}

extern "C" void kernel_launch(void* const* d_in, const int* in_sizes, int n_in,
                              void* d_out, int out_size, void* d_ws, size_t ws_size,
                              hipStream_t stream) {
  const float* x = (const float*)d_in[0];
  float* out = (float*)d_out;
  const int total = in_sizes[0];
  const int B = total / (T_LEN * NF);
  const int nblocks = B * NF;
  const int gpx = (B % 8 == 0) ? (B / 8) : 0;
  ts_feat_kernel<<<nblocks, NTH, 0, stream>>>(x, out, gpx);
}